// Round 16
// baseline (487.396 us; speedup 1.0000x reference)
//
#include <hip/hip_runtime.h>

#define N_NODES 100000
#define N_EDGES 3200000
#define D 256
#define NPAD 100032        // 1563 * 64 rows, covers gemm tiles
#define BCAP 128           // bucket capacity per row (max deg ~ 32+6sigma ~ 66)

#define GEMM_BLKS (NPAD / 64)        // 1563
#define PART_BLKS 782                // 4096 edges per partition block
#define CONV_BLKS 64                 // convert_wt sub-grid of part_conv
#define SCAT2_BLKS 768               // 96 blocks per stripe-group
#define GSTRIDE (96 * 256)
#define STRIPE 12500                 // rows per stripe (8 stripes)
#define SCAP 412000                  // stripe-list capacity (mean 400K + 20sigma)

typedef __attribute__((ext_vector_type(8))) short short8;
typedef __attribute__((ext_vector_type(8))) unsigned short ushort8;
typedef __attribute__((ext_vector_type(4))) float f32x4;
typedef __attribute__((ext_vector_type(4))) int i32x4;

static __device__ __forceinline__ unsigned short f2bf(float f) {
  unsigned u = __float_as_uint(f);
  u += 0x7FFF + ((u >> 16) & 1);  // round-to-nearest-even
  return (unsigned short)(u >> 16);
}
static __device__ __forceinline__ float bf2f(unsigned short h) {
  return __uint_as_float(((unsigned)h) << 16);
}

// ===========================================================================
// K1: partition edges into 8 XCD-stripe lists (blocks 0..PART_BLKS-1)
//     + convert_wt (blocks PART_BLKS..). One pass over the edge arrays.
// Stripe-list entry: {row, (bf16(val) sans sign)<<17 | col} (8B).
// Each block writes compacted runs (block-private -> no cross-XCD sharing).
// ===========================================================================
__global__ __launch_bounds__(256) void part_conv(
    const int* __restrict__ erow, const int* __restrict__ ecol,
    const float* __restrict__ eval_, int* __restrict__ scursor,
    uint2* __restrict__ slist, const float* __restrict__ W,
    ushort* __restrict__ wt) {
  const int tid = threadIdx.x;
  if (blockIdx.x >= PART_BLKS) {
    // convert_wt: wt[n][k] = bf16(W[k][n]); 4 n per block.
    int n = (blockIdx.x - PART_BLKS) * 4 + (tid >> 6);
    int k0 = (tid & 63) * 4;
    ushort4 o;
    o.x = f2bf(W[(size_t)(k0 + 0) * D + n]);
    o.y = f2bf(W[(size_t)(k0 + 1) * D + n]);
    o.z = f2bf(W[(size_t)(k0 + 2) * D + n]);
    o.w = f2bf(W[(size_t)(k0 + 3) * D + n]);
    *(ushort4*)(wt + (size_t)n * D + k0) = o;
    return;
  }

  __shared__ int lcnt[8], lbase[8];
  if (tid < 8) lcnt[tid] = 0;
  __syncthreads();

  int rank[16];
  const size_t ebase = (size_t)blockIdx.x * 4096;

  // Phase 1: per-stripe rank via LDS atomics (erow only).
  #pragma unroll
  for (int q = 0; q < 4; ++q) {
    size_t e0 = ebase + q * 1024 + tid * 4;
    if (e0 >= N_EDGES) continue;
    i32x4 r4 = *(const i32x4*)(erow + e0);
    rank[q * 4 + 0] = atomicAdd(&lcnt[r4.x / STRIPE], 1);
    rank[q * 4 + 1] = atomicAdd(&lcnt[r4.y / STRIPE], 1);
    rank[q * 4 + 2] = atomicAdd(&lcnt[r4.z / STRIPE], 1);
    rank[q * 4 + 3] = atomicAdd(&lcnt[r4.w / STRIPE], 1);
  }
  __syncthreads();
  if (tid < 8) lbase[tid] = atomicAdd(&scursor[tid], lcnt[tid]);
  __syncthreads();

  // Phase 2: write compacted entries (erow re-read is block-local L1/L2 hot).
  #pragma unroll
  for (int q = 0; q < 4; ++q) {
    size_t e0 = ebase + q * 1024 + tid * 4;
    if (e0 >= N_EDGES) continue;
    i32x4 r4 = *(const i32x4*)(erow + e0);
    i32x4 c4 = *(const i32x4*)(ecol + e0);
    f32x4 v4 = *(const f32x4*)(eval_ + e0);
    int s, p;
    s = r4.x / STRIPE; p = lbase[s] + rank[q * 4 + 0];
    if (p < SCAP)
      slist[(size_t)s * SCAP + p] =
          make_uint2((unsigned)r4.x, ((unsigned)f2bf(v4.x) << 17) | (unsigned)c4.x);
    s = r4.y / STRIPE; p = lbase[s] + rank[q * 4 + 1];
    if (p < SCAP)
      slist[(size_t)s * SCAP + p] =
          make_uint2((unsigned)r4.y, ((unsigned)f2bf(v4.y) << 17) | (unsigned)c4.y);
    s = r4.z / STRIPE; p = lbase[s] + rank[q * 4 + 2];
    if (p < SCAP)
      slist[(size_t)s * SCAP + p] =
          make_uint2((unsigned)r4.z, ((unsigned)f2bf(v4.z) << 17) | (unsigned)c4.z);
    s = r4.w / STRIPE; p = lbase[s] + rank[q * 4 + 3];
    if (p < SCAP)
      slist[(size_t)s * SCAP + p] =
          make_uint2((unsigned)r4.w, ((unsigned)f2bf(v4.w) << 17) | (unsigned)c4.w);
  }
}

// ===========================================================================
// K2: MFMA gemm (blocks 0..GEMM_BLKS-1) + stripe-list bucket scatter.
// Scatter group g = sid&7 (consistent XCD) consumes stripe-list g; every
// cnt/bucket line is written by one XCD group. Plain stores (L2 merges).
// ===========================================================================
__global__ __launch_bounds__(256) void gemm_scatter(
    const float* __restrict__ x, const ushort* __restrict__ wt,
    ushort* __restrict__ Y, const int* __restrict__ scursor,
    const uint2* __restrict__ slist, int* __restrict__ cnt,
    unsigned* __restrict__ buckets) {
  __shared__ ushort sA[64][264];  // used by gemm branch only
  const int tid = threadIdx.x;

  if (blockIdx.x >= GEMM_BLKS) {
    const int sid = blockIdx.x - GEMM_BLKS;
    const int g = sid & 7;
    const int sub = sid >> 3;  // 0..95
    int n = scursor[g];
    if (n > SCAP) n = SCAP;
    const uint2* __restrict__ sl = slist + (size_t)g * SCAP;
    for (int i = sub * 256 + tid; i < n; i += GSTRIDE) {
      uint2 e = sl[i];
      int r = (int)e.x;
      int j = atomicAdd(&cnt[r], 1);
      if (j < BCAP) buckets[(size_t)r * BCAP + j] = e.y;
    }
    return;
  }

  // ---- gemm path: Y[m0..m0+63][:] = bf16(f32(X)@bf16(W)) ----
  const int lane = tid & 63;
  const int wave = tid >> 6;
  const int m0 = blockIdx.x * 64;
  const int lrow = lane & 15;
  const int kch = (lane >> 4) * 8;

  #pragma unroll
  for (int it = 0; it < 16; ++it) {
    int idx = tid + it * 256;
    int row = idx >> 6;
    int c4 = idx & 63;
    int gr = m0 + row;
    if (gr >= N_NODES) gr = N_NODES - 1;
    float4 f = *(const float4*)(x + (size_t)gr * D + c4 * 4);
    ushort4 o;
    o.x = f2bf(f.x); o.y = f2bf(f.y); o.z = f2bf(f.z); o.w = f2bf(f.w);
    *(ushort4*)&sA[row][c4 * 4] = o;
  }
  __syncthreads();

  const int n0 = wave * 64;
  f32x4 acc[4][4];
  #pragma unroll
  for (int i = 0; i < 4; ++i)
    #pragma unroll
    for (int j = 0; j < 4; ++j) acc[i][j] = (f32x4){0.f, 0.f, 0.f, 0.f};

  const ushort* sb = wt + (size_t)(n0 + lrow) * D + kch;

  #pragma unroll
  for (int ks = 0; ks < 8; ++ks) {
    short8 a[4], b[4];
    #pragma unroll
    for (int i = 0; i < 4; ++i) {
      a[i] = *(const short8*)&sA[lrow + i * 16][kch + ks * 32];
      b[i] = *(const short8*)(sb + (size_t)i * 16 * D + ks * 32);
    }
    #pragma unroll
    for (int mi = 0; mi < 4; ++mi)
      #pragma unroll
      for (int ni = 0; ni < 4; ++ni)
        acc[mi][ni] = __builtin_amdgcn_mfma_f32_16x16x32_bf16(
            a[mi], b[ni], acc[mi][ni], 0, 0, 0);
  }

  // C/D: col = lane&15, row = (lane>>4)*4 + j.
  #pragma unroll
  for (int mi = 0; mi < 4; ++mi) {
    int rbase = m0 + mi * 16 + (lane >> 4) * 4;
    #pragma unroll
    for (int ni = 0; ni < 4; ++ni) {
      int col = n0 + ni * 16 + lrow;
      #pragma unroll
      for (int j = 0; j < 4; ++j)
        Y[(size_t)(rbase + j) * D + col] = f2bf(acc[mi][ni][j]);
    }
  }
}

// ===========================================================================
// out = relu(P @ Y): one wave per row; bucket layout [r*BCAP .. +cnt[r]).
// 32 lanes x 16B gathers; 2 edges across half-waves; 8-edge unroll;
// shfl_xor(32) combine. (r15-proven, unchanged.)
// ===========================================================================
__global__ __launch_bounds__(256) void row_accum_relu(
    const ushort* __restrict__ Y, const unsigned* __restrict__ buckets,
    const int* __restrict__ cnt, float* __restrict__ out) {
  const int lane = threadIdx.x & 63;
  const int l5 = lane & 31;
  const int sub = lane >> 5;
  int r = (int)((blockIdx.x << 2) + (threadIdx.x >> 6));
  r = __builtin_amdgcn_readfirstlane(r);
  if (r >= N_NODES) return;
  const unsigned* __restrict__ bk = buckets + (size_t)r * BCAP;
  const int end = min(cnt[r], BCAP);
  const int eo = l5 * 8;

  float acc[8] = {0.f, 0.f, 0.f, 0.f, 0.f, 0.f, 0.f, 0.f};

  int p = 0;
  for (; p + 8 <= end; p += 8) {
    uint2 q0 = *(const uint2*)(bk + p);
    uint2 q1 = *(const uint2*)(bk + p + 2);
    uint2 q2 = *(const uint2*)(bk + p + 4);
    uint2 q3 = *(const uint2*)(bk + p + 6);
    unsigned m0 = sub ? q0.y : q0.x;
    unsigned m1 = sub ? q1.y : q1.x;
    unsigned m2 = sub ? q2.y : q2.x;
    unsigned m3 = sub ? q3.y : q3.x;
    ushort8 g0 = *(const ushort8*)(Y + (size_t)(m0 & 0x1FFFF) * D + eo);
    ushort8 g1 = *(const ushort8*)(Y + (size_t)(m1 & 0x1FFFF) * D + eo);
    ushort8 g2 = *(const ushort8*)(Y + (size_t)(m2 & 0x1FFFF) * D + eo);
    ushort8 g3 = *(const ushort8*)(Y + (size_t)(m3 & 0x1FFFF) * D + eo);
    float v0 = __uint_as_float((m0 >> 17) << 16);
    float v1 = __uint_as_float((m1 >> 17) << 16);
    float v2 = __uint_as_float((m2 >> 17) << 16);
    float v3 = __uint_as_float((m3 >> 17) << 16);
    #pragma unroll
    for (int i = 0; i < 8; ++i) acc[i] = fmaf(v0, bf2f(g0[i]), acc[i]);
    #pragma unroll
    for (int i = 0; i < 8; ++i) acc[i] = fmaf(v1, bf2f(g1[i]), acc[i]);
    #pragma unroll
    for (int i = 0; i < 8; ++i) acc[i] = fmaf(v2, bf2f(g2[i]), acc[i]);
    #pragma unroll
    for (int i = 0; i < 8; ++i) acc[i] = fmaf(v3, bf2f(g3[i]), acc[i]);
  }
  for (; p < end; p += 2) {  // tail pairs; in-bucket reads always in-bounds
    uint2 q = *(const uint2*)(bk + p);
    unsigned m = (p + sub < end) ? (sub ? q.y : q.x) : 0u;  // mask poison
    float v = __uint_as_float((m >> 17) << 16);
    ushort8 g = *(const ushort8*)(Y + (size_t)(m & 0x1FFFF) * D + eo);
    #pragma unroll
    for (int i = 0; i < 8; ++i) acc[i] = fmaf(v, bf2f(g[i]), acc[i]);
  }

  #pragma unroll
  for (int i = 0; i < 8; ++i) acc[i] += __shfl_xor(acc[i], 32, 64);

  float4 o;
  if (sub == 0) o = make_float4(acc[0], acc[1], acc[2], acc[3]);
  else          o = make_float4(acc[4], acc[5], acc[6], acc[7]);
  o.x = fmaxf(o.x, 0.f); o.y = fmaxf(o.y, 0.f);
  o.z = fmaxf(o.z, 0.f); o.w = fmaxf(o.w, 0.f);
  *(float4*)(out + (size_t)r * D + eo + sub * 4) = o;
}

// ===========================================================================
// Fallback path B (round-2, proven): f32 CSR accumulate + f32 VALU GEMM.
// ===========================================================================
__global__ __launch_bounds__(256) void hist_kernel(
    const int* __restrict__ erow, int* __restrict__ cnt) {
  int stride = gridDim.x * blockDim.x;
  for (int e = blockIdx.x * blockDim.x + threadIdx.x; e < N_EDGES; e += stride)
    atomicAdd(&cnt[erow[e]], 1);
}

__global__ __launch_bounds__(1024) void scan_kernel(
    int* __restrict__ cnt, int* __restrict__ row_ptr) {
  __shared__ int partial[1024];
  const int T = 1024;
  const int per = (N_NODES + T - 1) / T;
  int tid = threadIdx.x;
  int base = tid * per;
  int sum = 0;
  for (int i = 0; i < per; ++i) {
    int idx = base + i;
    if (idx < N_NODES) sum += cnt[idx];
  }
  partial[tid] = sum;
  __syncthreads();
  for (int off = 1; off < T; off <<= 1) {
    int v = (tid >= off) ? partial[tid - off] : 0;
    __syncthreads();
    partial[tid] += v;
    __syncthreads();
  }
  int run = (tid == 0) ? 0 : partial[tid - 1];
  for (int i = 0; i < per; ++i) {
    int idx = base + i;
    if (idx < N_NODES) {
      row_ptr[idx] = run;
      run += cnt[idx];
      cnt[idx] = 0;
    }
  }
  if (tid == T - 1) row_ptr[N_NODES] = run;
}

__global__ __launch_bounds__(256) void sort_scatter_kernel(
    const int* __restrict__ erow, const int* __restrict__ ecol,
    const float* __restrict__ eval_, const int* __restrict__ row_ptr,
    int* __restrict__ cursor, int2* __restrict__ sorted) {
  int e = blockIdx.x * blockDim.x + threadIdx.x;
  if (e >= N_EDGES) return;
  int r = erow[e];
  int pos = row_ptr[r] + atomicAdd(&cursor[r], 1);
  sorted[pos] = make_int2(ecol[e], __float_as_int(eval_[e]));
}

__global__ __launch_bounds__(256) void row_accum_kernel(
    const float* __restrict__ x, const int2* __restrict__ sorted,
    const int* __restrict__ row_ptr, float* __restrict__ support) {
  int lane = threadIdx.x & 63;
  int r = (int)((blockIdx.x * blockDim.x + threadIdx.x) >> 6);
  if (r >= N_NODES) return;
  int beg = row_ptr[r];
  int end = row_ptr[r + 1];
  const float4* __restrict__ x4 = (const float4*)x;
  float4 acc = make_float4(0.f, 0.f, 0.f, 0.f);
  int p = beg;
  for (; p + 1 < end; p += 2) {
    int2 cv0 = sorted[p];
    int2 cv1 = sorted[p + 1];
    float4 xv0 = x4[(size_t)cv0.x * 64 + lane];
    float4 xv1 = x4[(size_t)cv1.x * 64 + lane];
    float v0 = __int_as_float(cv0.y);
    float v1 = __int_as_float(cv1.y);
    acc.x = fmaf(v0, xv0.x, acc.x); acc.y = fmaf(v0, xv0.y, acc.y);
    acc.z = fmaf(v0, xv0.z, acc.z); acc.w = fmaf(v0, xv0.w, acc.w);
    acc.x = fmaf(v1, xv1.x, acc.x); acc.y = fmaf(v1, xv1.y, acc.y);
    acc.z = fmaf(v1, xv1.z, acc.z); acc.w = fmaf(v1, xv1.w, acc.w);
  }
  if (p < end) {
    int2 cv = sorted[p];
    float v = __int_as_float(cv.y);
    float4 xv = x4[(size_t)cv.x * 64 + lane];
    acc.x = fmaf(v, xv.x, acc.x); acc.y = fmaf(v, xv.y, acc.y);
    acc.z = fmaf(v, xv.z, acc.z); acc.w = fmaf(v, xv.w, acc.w);
  }
  ((float4*)support)[(size_t)r * 64 + lane] = acc;
}

__global__ __launch_bounds__(256) void scatter_kernel(
    const float* __restrict__ x, const int* __restrict__ erow,
    const int* __restrict__ ecol, const float* __restrict__ eval_,
    float* __restrict__ support, int nwaves) {
  int lane = threadIdx.x & 63;
  int wave = __builtin_amdgcn_readfirstlane(
      (int)((blockIdx.x * blockDim.x + threadIdx.x) >> 6));
  for (int e = wave; e < N_EDGES; e += nwaves) {
    int r = erow[e];
    int c = ecol[e];
    float v = eval_[e];
    float4 xv = ((const float4*)(x + (size_t)c * D))[lane];
    float* dst = support + (size_t)r * D + lane * 4;
    atomicAdd(dst + 0, v * xv.x);
    atomicAdd(dst + 1, v * xv.y);
    atomicAdd(dst + 2, v * xv.z);
    atomicAdd(dst + 3, v * xv.w);
  }
}

__global__ __launch_bounds__(256) void gemm_relu_inplace(
    const float* __restrict__ W, float* __restrict__ io) {
  __shared__ float s[32][D];
  const int tid = threadIdx.x;
  const int row0 = blockIdx.x * 32;
  {
    const float4* src = (const float4*)(io + (size_t)row0 * D);
    float4* sd = (float4*)&s[0][0];
    #pragma unroll
    for (int t = 0; t < 8; ++t) sd[tid + t * 256] = src[tid + t * 256];
  }
  __syncthreads();
  const int j0 = (tid & 63) * 4;
  const int i0 = (tid >> 6) * 8;
  float acc[8][4];
  #pragma unroll
  for (int i = 0; i < 8; ++i)
    for (int q = 0; q < 4; ++q) acc[i][q] = 0.f;
  #pragma unroll 4
  for (int k = 0; k < D; ++k) {
    float4 w4 = *(const float4*)(W + (size_t)k * D + j0);
    #pragma unroll
    for (int i = 0; i < 8; ++i) {
      float sv = s[i0 + i][k];
      acc[i][0] = fmaf(sv, w4.x, acc[i][0]);
      acc[i][1] = fmaf(sv, w4.y, acc[i][1]);
      acc[i][2] = fmaf(sv, w4.z, acc[i][2]);
      acc[i][3] = fmaf(sv, w4.w, acc[i][3]);
    }
  }
  #pragma unroll
  for (int i = 0; i < 8; ++i) {
    float4 o;
    o.x = fmaxf(acc[i][0], 0.f);
    o.y = fmaxf(acc[i][1], 0.f);
    o.z = fmaxf(acc[i][2], 0.f);
    o.w = fmaxf(acc[i][3], 0.f);
    *(float4*)(io + (size_t)(row0 + i0 + i) * D + j0) = o;
  }
}

extern "C" void kernel_launch(void* const* d_in, const int* in_sizes, int n_in,
                              void* d_out, int out_size, void* d_ws, size_t ws_size,
                              hipStream_t stream) {
  const float* x     = (const float*)d_in[0];
  const int*   erow  = (const int*)d_in[1];
  const int*   ecol  = (const int*)d_in[2];
  const float* eval_ = (const float*)d_in[3];
  const float* W     = (const float*)d_in[4];
  float* out = (float*)d_out;

  // Path A workspace: cnt | scursor | stripe lists | buckets | Y | wt (~129 MB)
  const size_t cnt_b    = (size_t)N_NODES * sizeof(int);          // 400000 (64-mult)
  const size_t off_scur = cnt_b;                                  // 8 ints + pad
  const size_t off_sl   = off_scur + 64;
  const size_t sl_b     = (size_t)8 * SCAP * 8;                   // 26.37 MB
  const size_t off_bkt  = ((off_sl + sl_b + 63) / 64) * 64;
  const size_t bkt_b    = (size_t)N_NODES * BCAP * 4;             // 51.2 MB
  const size_t off_Y    = off_bkt + bkt_b;
  const size_t Y_b      = (size_t)NPAD * D * 2;                   // 51.2 MB
  const size_t off_wt   = off_Y + Y_b;
  const size_t wt_b     = (size_t)D * D * 2;
  const size_t need_A   = off_wt + wt_b;                          // ~129.1 MB

  // Path A2 (r15, no stripe lists): ~103 MB.  Path B (CSR f32): ~26.4 MB.
  const size_t rp_b       = (size_t)(N_NODES + 1) * sizeof(int);
  const size_t off_sorted = ((cnt_b + rp_b + 15) / 16) * 16;
  const size_t sortedB_b  = (size_t)(N_EDGES + 2) * 8;
  const size_t need_B     = off_sorted + sortedB_b;

  if (ws_size >= need_A) {
    int*      cnt     = (int*)d_ws;
    int*      scursor = (int*)((char*)d_ws + off_scur);
    uint2*    slist   = (uint2*)((char*)d_ws + off_sl);
    unsigned* buckets = (unsigned*)((char*)d_ws + off_bkt);
    ushort*   Y       = (ushort*)((char*)d_ws + off_Y);
    ushort*   wt      = (ushort*)((char*)d_ws + off_wt);

    hipMemsetAsync(d_ws, 0, cnt_b + 64, stream);  // cnt + scursor
    part_conv<<<PART_BLKS + CONV_BLKS, 256, 0, stream>>>(
        erow, ecol, eval_, scursor, slist, W, wt);
    gemm_scatter<<<GEMM_BLKS + SCAT2_BLKS, 256, 0, stream>>>(
        x, wt, Y, scursor, slist, cnt, buckets);
    row_accum_relu<<<(N_NODES + 3) / 4, 256, 0, stream>>>(
        Y, buckets, cnt, out);
  } else if (ws_size >= need_B) {
    int*  cnt     = (int*)d_ws;
    int*  row_ptr = (int*)((char*)d_ws + cnt_b);
    int2* sorted  = (int2*)((char*)d_ws + off_sorted);

    hipMemsetAsync(cnt, 0, cnt_b, stream);
    hist_kernel<<<2048, 256, 0, stream>>>(erow, cnt);
    scan_kernel<<<1, 1024, 0, stream>>>(cnt, row_ptr);
    sort_scatter_kernel<<<(N_EDGES + 255) / 256, 256, 0, stream>>>(
        erow, ecol, eval_, row_ptr, cnt, sorted);
    row_accum_kernel<<<(N_NODES * 64 + 255) / 256, 256, 0, stream>>>(
        x, sorted, row_ptr, out);
    gemm_relu_inplace<<<N_NODES / 32, 256, 0, stream>>>(W, out);
  } else {
    hipMemsetAsync(out, 0, (size_t)N_NODES * D * sizeof(float), stream);
    const int blocks = 2048;
    const int nwaves = blocks * (256 / 64);
    scatter_kernel<<<blocks, 256, 0, stream>>>(x, erow, ecol, eval_, out, nwaves);
    gemm_relu_inplace<<<N_NODES / 32, 256, 0, stream>>>(W, out);
  }
}

// Round 17
// 424.893 us; speedup vs baseline: 1.1471x; 1.1471x over previous
//
#include <hip/hip_runtime.h>

#define N_NODES 100000
#define N_EDGES 3200000
#define D 256
#define NPAD 100032        // 1563 * 64 rows, covers gemm tiles
#define BCAP 128           // bucket capacity per row (P(deg>=128)~1e-35)

#define GEMM_BLKS (NPAD / 64)        // 1563
#define NCHUNK 782                   // ceil(3.2e6 / 4096)
#define SCAT_BLKS (NCHUNK * 8)       // 6256 (8 XCD-groups per chunk)
#define ROWS_PER_G 12500             // 8 * 12500 = 100000

typedef __attribute__((ext_vector_type(8))) short short8;
typedef __attribute__((ext_vector_type(8))) unsigned short ushort8;
typedef __attribute__((ext_vector_type(4))) float f32x4;
typedef __attribute__((ext_vector_type(4))) int i32x4;

static __device__ __forceinline__ unsigned short f2bf(float f) {
  unsigned u = __float_as_uint(f);
  u += 0x7FFF + ((u >> 16) & 1);  // round-to-nearest-even
  return (unsigned short)(u >> 16);
}
static __device__ __forceinline__ float bf2f(unsigned short h) {
  return __uint_as_float(((unsigned)h) << 16);
}

// ===========================================================================
// wt[n][k] = bf16(W[k][n])
// ===========================================================================
__global__ __launch_bounds__(64) void convert_wt(
    const float* __restrict__ W, ushort* __restrict__ wt) {
  int n = blockIdx.x;
  int k0 = threadIdx.x * 4;
  ushort4 o;
  o.x = f2bf(W[(size_t)(k0 + 0) * D + n]);
  o.y = f2bf(W[(size_t)(k0 + 1) * D + n]);
  o.z = f2bf(W[(size_t)(k0 + 2) * D + n]);
  o.w = f2bf(W[(size_t)(k0 + 3) * D + n]);
  *(ushort4*)(wt + (size_t)n * D + k0) = o;
}

// ===========================================================================
// Fused: MFMA gemm (blocks 0..GEMM_BLKS-1) + XCD-bucketed BUCKET scatter.
// No CSR: edge -> buckets[row][atomicAdd(cnt[row])]. Packed 4B edges:
// (bf16(val) sans sign)<<17 | col. Group g = bid&7 takes rows in its 1/8
// stripe so each bucket/cnt line is written by one XCD group.
// ===========================================================================
__global__ __launch_bounds__(256) void gemm_scatter(
    const float* __restrict__ x, const ushort* __restrict__ wt,
    ushort* __restrict__ Y, const int* __restrict__ erow,
    const int* __restrict__ ecol, const float* __restrict__ eval_,
    int* __restrict__ cnt, unsigned* __restrict__ buckets) {
  __shared__ ushort sA[64][264];  // used by gemm branch only
  const int tid = threadIdx.x;

  if (blockIdx.x >= GEMM_BLKS) {
    const int sid = blockIdx.x - GEMM_BLKS;   // 0..SCAT_BLKS-1
    const int g = blockIdx.x & 7;             // XCD-ish group
    const int chunk = sid >> 3;               // 0..NCHUNK-1
    const int lo = g * ROWS_PER_G;
    const int hi = lo + ROWS_PER_G;
    const size_t ebase = (size_t)chunk * 4096;

    #pragma unroll
    for (int q = 0; q < 4; ++q) {
      size_t e0 = ebase + q * 1024 + tid * 4;
      if (e0 >= N_EDGES) continue;  // tail chunk
      i32x4 r4 = *(const i32x4*)(erow + e0);
      bool m0 = (r4.x >= lo) & (r4.x < hi);
      bool m1 = (r4.y >= lo) & (r4.y < hi);
      bool m2 = (r4.z >= lo) & (r4.z < hi);
      bool m3 = (r4.w >= lo) & (r4.w < hi);
      if (!(m0 | m1 | m2 | m3)) continue;     // quick reject (~59%)
      i32x4 c4 = *(const i32x4*)(ecol + e0);
      f32x4 v4 = *(const f32x4*)(eval_ + e0);
      if (m0) {
        int j = atomicAdd(&cnt[r4.x], 1);
        if (j < BCAP)
          buckets[(size_t)r4.x * BCAP + j] =
              ((unsigned)f2bf(v4.x) << 17) | (unsigned)c4.x;
      }
      if (m1) {
        int j = atomicAdd(&cnt[r4.y], 1);
        if (j < BCAP)
          buckets[(size_t)r4.y * BCAP + j] =
              ((unsigned)f2bf(v4.y) << 17) | (unsigned)c4.y;
      }
      if (m2) {
        int j = atomicAdd(&cnt[r4.z], 1);
        if (j < BCAP)
          buckets[(size_t)r4.z * BCAP + j] =
              ((unsigned)f2bf(v4.z) << 17) | (unsigned)c4.z;
      }
      if (m3) {
        int j = atomicAdd(&cnt[r4.w], 1);
        if (j < BCAP)
          buckets[(size_t)r4.w * BCAP + j] =
              ((unsigned)f2bf(v4.w) << 17) | (unsigned)c4.w;
      }
    }
    return;
  }

  // ---- gemm path: Y[m0..m0+63][:] = bf16(f32(X)@bf16(W)) ----
  const int lane = tid & 63;
  const int wave = tid >> 6;
  const int m0 = blockIdx.x * 64;
  const int lrow = lane & 15;
  const int kch = (lane >> 4) * 8;

  #pragma unroll
  for (int it = 0; it < 16; ++it) {
    int idx = tid + it * 256;
    int row = idx >> 6;
    int c4 = idx & 63;
    int gr = m0 + row;
    if (gr >= N_NODES) gr = N_NODES - 1;
    float4 f = *(const float4*)(x + (size_t)gr * D + c4 * 4);
    ushort4 o;
    o.x = f2bf(f.x); o.y = f2bf(f.y); o.z = f2bf(f.z); o.w = f2bf(f.w);
    *(ushort4*)&sA[row][c4 * 4] = o;
  }
  __syncthreads();

  const int n0 = wave * 64;
  f32x4 acc[4][4];
  #pragma unroll
  for (int i = 0; i < 4; ++i)
    #pragma unroll
    for (int j = 0; j < 4; ++j) acc[i][j] = (f32x4){0.f, 0.f, 0.f, 0.f};

  const ushort* sb = wt + (size_t)(n0 + lrow) * D + kch;

  #pragma unroll
  for (int ks = 0; ks < 8; ++ks) {
    short8 a[4], b[4];
    #pragma unroll
    for (int i = 0; i < 4; ++i) {
      a[i] = *(const short8*)&sA[lrow + i * 16][kch + ks * 32];
      b[i] = *(const short8*)(sb + (size_t)i * 16 * D + ks * 32);
    }
    #pragma unroll
    for (int mi = 0; mi < 4; ++mi)
      #pragma unroll
      for (int ni = 0; ni < 4; ++ni)
        acc[mi][ni] = __builtin_amdgcn_mfma_f32_16x16x32_bf16(
            a[mi], b[ni], acc[mi][ni], 0, 0, 0);
  }

  // C/D: col = lane&15, row = (lane>>4)*4 + j.
  #pragma unroll
  for (int mi = 0; mi < 4; ++mi) {
    int rbase = m0 + mi * 16 + (lane >> 4) * 4;
    #pragma unroll
    for (int ni = 0; ni < 4; ++ni) {
      int col = n0 + ni * 16 + lrow;
      #pragma unroll
      for (int j = 0; j < 4; ++j)
        Y[(size_t)(rbase + j) * D + col] = f2bf(acc[mi][ni][j]);
    }
  }
}

// ===========================================================================
// out = relu(P @ Y): one wave per row; bucket layout [r*BCAP .. +cnt[r]).
// beg is always 16B-aligned -> no peel. 32 lanes x 16B gathers; 2 edges
// across half-waves; 8-edge unroll; shfl_xor(32) combine.
// ===========================================================================
__global__ __launch_bounds__(256) void row_accum_relu(
    const ushort* __restrict__ Y, const unsigned* __restrict__ buckets,
    const int* __restrict__ cnt, float* __restrict__ out) {
  const int lane = threadIdx.x & 63;
  const int l5 = lane & 31;
  const int sub = lane >> 5;
  int r = (int)((blockIdx.x << 2) + (threadIdx.x >> 6));
  r = __builtin_amdgcn_readfirstlane(r);
  if (r >= N_NODES) return;
  const unsigned* __restrict__ bk = buckets + (size_t)r * BCAP;
  const int end = min(cnt[r], BCAP);
  const int eo = l5 * 8;

  float acc[8] = {0.f, 0.f, 0.f, 0.f, 0.f, 0.f, 0.f, 0.f};

  int p = 0;
  for (; p + 8 <= end; p += 8) {
    uint2 q0 = *(const uint2*)(bk + p);
    uint2 q1 = *(const uint2*)(bk + p + 2);
    uint2 q2 = *(const uint2*)(bk + p + 4);
    uint2 q3 = *(const uint2*)(bk + p + 6);
    unsigned m0 = sub ? q0.y : q0.x;
    unsigned m1 = sub ? q1.y : q1.x;
    unsigned m2 = sub ? q2.y : q2.x;
    unsigned m3 = sub ? q3.y : q3.x;
    ushort8 g0 = *(const ushort8*)(Y + (size_t)(m0 & 0x1FFFF) * D + eo);
    ushort8 g1 = *(const ushort8*)(Y + (size_t)(m1 & 0x1FFFF) * D + eo);
    ushort8 g2 = *(const ushort8*)(Y + (size_t)(m2 & 0x1FFFF) * D + eo);
    ushort8 g3 = *(const ushort8*)(Y + (size_t)(m3 & 0x1FFFF) * D + eo);
    float v0 = __uint_as_float((m0 >> 17) << 16);
    float v1 = __uint_as_float((m1 >> 17) << 16);
    float v2 = __uint_as_float((m2 >> 17) << 16);
    float v3 = __uint_as_float((m3 >> 17) << 16);
    #pragma unroll
    for (int i = 0; i < 8; ++i) acc[i] = fmaf(v0, bf2f(g0[i]), acc[i]);
    #pragma unroll
    for (int i = 0; i < 8; ++i) acc[i] = fmaf(v1, bf2f(g1[i]), acc[i]);
    #pragma unroll
    for (int i = 0; i < 8; ++i) acc[i] = fmaf(v2, bf2f(g2[i]), acc[i]);
    #pragma unroll
    for (int i = 0; i < 8; ++i) acc[i] = fmaf(v3, bf2f(g3[i]), acc[i]);
  }
  for (; p < end; p += 2) {  // tail pairs; in-bucket reads always in-bounds
    uint2 q = *(const uint2*)(bk + p);
    unsigned m = (p + sub < end) ? (sub ? q.y : q.x) : 0u;  // mask poison
    float v = __uint_as_float((m >> 17) << 16);
    ushort8 g = *(const ushort8*)(Y + (size_t)(m & 0x1FFFF) * D + eo);
    #pragma unroll
    for (int i = 0; i < 8; ++i) acc[i] = fmaf(v, bf2f(g[i]), acc[i]);
  }

  #pragma unroll
  for (int i = 0; i < 8; ++i) acc[i] += __shfl_xor(acc[i], 32, 64);

  float4 o;
  if (sub == 0) o = make_float4(acc[0], acc[1], acc[2], acc[3]);
  else          o = make_float4(acc[4], acc[5], acc[6], acc[7]);
  o.x = fmaxf(o.x, 0.f); o.y = fmaxf(o.y, 0.f);
  o.z = fmaxf(o.z, 0.f); o.w = fmaxf(o.w, 0.f);
  *(float4*)(out + (size_t)r * D + eo + sub * 4) = o;
}

// ===========================================================================
// Fallback path B (round-2, proven): f32 CSR accumulate + f32 VALU GEMM.
// ===========================================================================
__global__ __launch_bounds__(256) void hist_kernel(
    const int* __restrict__ erow, int* __restrict__ cnt) {
  int stride = gridDim.x * blockDim.x;
  for (int e = blockIdx.x * blockDim.x + threadIdx.x; e < N_EDGES; e += stride)
    atomicAdd(&cnt[erow[e]], 1);
}

__global__ __launch_bounds__(1024) void scan_kernel(
    int* __restrict__ cnt, int* __restrict__ row_ptr) {
  __shared__ int partial[1024];
  const int T = 1024;
  const int per = (N_NODES + T - 1) / T;
  int tid = threadIdx.x;
  int base = tid * per;
  int sum = 0;
  for (int i = 0; i < per; ++i) {
    int idx = base + i;
    if (idx < N_NODES) sum += cnt[idx];
  }
  partial[tid] = sum;
  __syncthreads();
  for (int off = 1; off < T; off <<= 1) {
    int v = (tid >= off) ? partial[tid - off] : 0;
    __syncthreads();
    partial[tid] += v;
    __syncthreads();
  }
  int run = (tid == 0) ? 0 : partial[tid - 1];
  for (int i = 0; i < per; ++i) {
    int idx = base + i;
    if (idx < N_NODES) {
      row_ptr[idx] = run;
      run += cnt[idx];
      cnt[idx] = 0;
    }
  }
  if (tid == T - 1) row_ptr[N_NODES] = run;
}

__global__ __launch_bounds__(256) void sort_scatter_kernel(
    const int* __restrict__ erow, const int* __restrict__ ecol,
    const float* __restrict__ eval_, const int* __restrict__ row_ptr,
    int* __restrict__ cursor, int2* __restrict__ sorted) {
  int e = blockIdx.x * blockDim.x + threadIdx.x;
  if (e >= N_EDGES) return;
  int r = erow[e];
  int pos = row_ptr[r] + atomicAdd(&cursor[r], 1);
  sorted[pos] = make_int2(ecol[e], __float_as_int(eval_[e]));
}

__global__ __launch_bounds__(256) void row_accum_kernel(
    const float* __restrict__ x, const int2* __restrict__ sorted,
    const int* __restrict__ row_ptr, float* __restrict__ support) {
  int lane = threadIdx.x & 63;
  int r = (int)((blockIdx.x * blockDim.x + threadIdx.x) >> 6);
  if (r >= N_NODES) return;
  int beg = row_ptr[r];
  int end = row_ptr[r + 1];
  const float4* __restrict__ x4 = (const float4*)x;
  float4 acc = make_float4(0.f, 0.f, 0.f, 0.f);
  int p = beg;
  for (; p + 1 < end; p += 2) {
    int2 cv0 = sorted[p];
    int2 cv1 = sorted[p + 1];
    float4 xv0 = x4[(size_t)cv0.x * 64 + lane];
    float4 xv1 = x4[(size_t)cv1.x * 64 + lane];
    float v0 = __int_as_float(cv0.y);
    float v1 = __int_as_float(cv1.y);
    acc.x = fmaf(v0, xv0.x, acc.x); acc.y = fmaf(v0, xv0.y, acc.y);
    acc.z = fmaf(v0, xv0.z, acc.z); acc.w = fmaf(v0, xv0.w, acc.w);
    acc.x = fmaf(v1, xv1.x, acc.x); acc.y = fmaf(v1, xv1.y, acc.y);
    acc.z = fmaf(v1, xv1.z, acc.z); acc.w = fmaf(v1, xv1.w, acc.w);
  }
  if (p < end) {
    int2 cv = sorted[p];
    float v = __int_as_float(cv.y);
    float4 xv = x4[(size_t)cv.x * 64 + lane];
    acc.x = fmaf(v, xv.x, acc.x); acc.y = fmaf(v, xv.y, acc.y);
    acc.z = fmaf(v, xv.z, acc.z); acc.w = fmaf(v, xv.w, acc.w);
  }
  ((float4*)support)[(size_t)r * 64 + lane] = acc;
}

__global__ __launch_bounds__(256) void scatter_kernel(
    const float* __restrict__ x, const int* __restrict__ erow,
    const int* __restrict__ ecol, const float* __restrict__ eval_,
    float* __restrict__ support, int nwaves) {
  int lane = threadIdx.x & 63;
  int wave = __builtin_amdgcn_readfirstlane(
      (int)((blockIdx.x * blockDim.x + threadIdx.x) >> 6));
  for (int e = wave; e < N_EDGES; e += nwaves) {
    int r = erow[e];
    int c = ecol[e];
    float v = eval_[e];
    float4 xv = ((const float4*)(x + (size_t)c * D))[lane];
    float* dst = support + (size_t)r * D + lane * 4;
    atomicAdd(dst + 0, v * xv.x);
    atomicAdd(dst + 1, v * xv.y);
    atomicAdd(dst + 2, v * xv.z);
    atomicAdd(dst + 3, v * xv.w);
  }
}

__global__ __launch_bounds__(256) void gemm_relu_inplace(
    const float* __restrict__ W, float* __restrict__ io) {
  __shared__ float s[32][D];
  const int tid = threadIdx.x;
  const int row0 = blockIdx.x * 32;
  {
    const float4* src = (const float4*)(io + (size_t)row0 * D);
    float4* sd = (float4*)&s[0][0];
    #pragma unroll
    for (int t = 0; t < 8; ++t) sd[tid + t * 256] = src[tid + t * 256];
  }
  __syncthreads();
  const int j0 = (tid & 63) * 4;
  const int i0 = (tid >> 6) * 8;
  float acc[8][4];
  #pragma unroll
  for (int i = 0; i < 8; ++i)
    for (int q = 0; q < 4; ++q) acc[i][q] = 0.f;
  #pragma unroll 4
  for (int k = 0; k < D; ++k) {
    float4 w4 = *(const float4*)(W + (size_t)k * D + j0);
    #pragma unroll
    for (int i = 0; i < 8; ++i) {
      float sv = s[i0 + i][k];
      acc[i][0] = fmaf(sv, w4.x, acc[i][0]);
      acc[i][1] = fmaf(sv, w4.y, acc[i][1]);
      acc[i][2] = fmaf(sv, w4.z, acc[i][2]);
      acc[i][3] = fmaf(sv, w4.w, acc[i][3]);
    }
  }
  #pragma unroll
  for (int i = 0; i < 8; ++i) {
    float4 o;
    o.x = fmaxf(acc[i][0], 0.f);
    o.y = fmaxf(acc[i][1], 0.f);
    o.z = fmaxf(acc[i][2], 0.f);
    o.w = fmaxf(acc[i][3], 0.f);
    *(float4*)(io + (size_t)(row0 + i0 + i) * D + j0) = o;
  }
}

extern "C" void kernel_launch(void* const* d_in, const int* in_sizes, int n_in,
                              void* d_out, int out_size, void* d_ws, size_t ws_size,
                              hipStream_t stream) {
  const float* x     = (const float*)d_in[0];
  const int*   erow  = (const int*)d_in[1];
  const int*   ecol  = (const int*)d_in[2];
  const float* eval_ = (const float*)d_in[3];
  const float* W     = (const float*)d_in[4];
  float* out = (float*)d_out;

  // Path A workspace: cnt + fixed-capacity buckets + Y + wt (~103 MB)
  const size_t cnt_b      = (size_t)N_NODES * sizeof(int);          // 400 KB
  const size_t off_bkt    = ((cnt_b + 63) / 64) * 64;
  const size_t bkt_b      = (size_t)N_NODES * BCAP * 4;             // 51.2 MB
  const size_t off_Y      = off_bkt + bkt_b;
  const size_t Y_b        = (size_t)NPAD * D * 2;                   // 51.2 MB
  const size_t off_wt     = off_Y + Y_b;
  const size_t wt_b       = (size_t)D * D * 2;
  const size_t need_A     = off_wt + wt_b;                          // ~103 MB

  // Path B workspace (round-2 CSR): ~26.4 MB
  const size_t rp_b       = (size_t)(N_NODES + 1) * sizeof(int);
  const size_t off_sorted = ((cnt_b + rp_b + 15) / 16) * 16;
  const size_t sortedB_b  = (size_t)(N_EDGES + 2) * 8;
  const size_t need_B     = off_sorted + sortedB_b;

  if (ws_size >= need_A) {
    int*      cnt     = (int*)d_ws;
    unsigned* buckets = (unsigned*)((char*)d_ws + off_bkt);
    ushort*   Y       = (ushort*)((char*)d_ws + off_Y);
    ushort*   wt      = (ushort*)((char*)d_ws + off_wt);

    hipMemsetAsync(cnt, 0, cnt_b, stream);
    convert_wt<<<D, 64, 0, stream>>>(W, wt);
    gemm_scatter<<<GEMM_BLKS + SCAT_BLKS, 256, 0, stream>>>(
        x, wt, Y, erow, ecol, eval_, cnt, buckets);
    row_accum_relu<<<(N_NODES + 3) / 4, 256, 0, stream>>>(
        Y, buckets, cnt, out);
  } else if (ws_size >= need_B) {
    int*  cnt     = (int*)d_ws;
    int*  row_ptr = (int*)((char*)d_ws + cnt_b);
    int2* sorted  = (int2*)((char*)d_ws + off_sorted);

    hipMemsetAsync(cnt, 0, cnt_b, stream);
    hist_kernel<<<2048, 256, 0, stream>>>(erow, cnt);
    scan_kernel<<<1, 1024, 0, stream>>>(cnt, row_ptr);
    sort_scatter_kernel<<<(N_EDGES + 255) / 256, 256, 0, stream>>>(
        erow, ecol, eval_, row_ptr, cnt, sorted);
    row_accum_kernel<<<(N_NODES * 64 + 255) / 256, 256, 0, stream>>>(
        x, sorted, row_ptr, out);
    gemm_relu_inplace<<<N_NODES / 32, 256, 0, stream>>>(W, out);
  } else {
    hipMemsetAsync(out, 0, (size_t)N_NODES * D * sizeof(float), stream);
    const int blocks = 2048;
    const int nwaves = blocks * (256 / 64);
    scatter_kernel<<<blocks, 256, 0, stream>>>(x, erow, ecol, eval_, out, nwaves);
    gemm_relu_inplace<<<N_NODES / 32, 256, 0, stream>>>(W, out);
  }
}